// Round 15
// baseline (435.861 us; speedup 1.0000x reference)
//
#include <hip/hip_runtime.h>
#include <hip/hip_bf16.h>
#include <math.h>

// NoisyTopkRouter: rows=32768, D=4096, E=64, k=8.
// R15: fully-decoupled waves, ZERO barriers in the K loop.
// Wave = 16 rows x 32 vcols x full K. W: wave-private gl16 DMA -> LDS
// (2-deep, per-wave vmcnt; no cross-wave sharing). h: global->reg, 3-tile
// prefetch (4 named sets), fp16x2 split at consume. 6 MFMA/tile/wave.
// Output (fp32): gates[rows*64] | ix[rows*8] | full[rows*64]

typedef __attribute__((ext_vector_type(8))) _Float16 f16x8;
typedef __attribute__((ext_vector_type(4))) float f32x4;
typedef unsigned int u32;

#define D_DIM 4096
#define NT 128               // k-tiles of 32
#define WTILE_BYTES 16384    // per-k-tile W image: 2 planes x 8KB

__device__ __forceinline__ float softplus_f(float x) {
    return fmaxf(x, 0.0f) + log1pf(expf(-fabsf(x)));
}

__device__ __forceinline__ void gl16(void* lds, const void* g) {
    __builtin_amdgcn_global_load_lds(
        (const __attribute__((address_space(1))) u32*)g,
        (__attribute__((address_space(3))) u32*)lds, 16, 0, 0);
}

#define MFMA16F(A, B, C) __builtin_amdgcn_mfma_f32_16x16x32_f16((A), (B), (C), 0, 0, 0)

// ---- W pre-conversion (unchanged): 2 fp16 planes (p0=f16(w), p1=f16((w-p0)*2048)),
// per-k-tile 16KB image, chunk-swizzled sc = c4 ^ ((vrow>>2)&3)
__global__ __launch_bounds__(256)
void wconv_kernel(const float* __restrict__ Ww, const float* __restrict__ Wn,
                  char* __restrict__ Wp)
{
    const int bid = blockIdx.x;            // 256 blocks
    const int kc = bid >> 1, half = bid & 1;
    const int t = threadIdx.x;
    const int vrow = half * 64 + (t >> 2);
    const int c4 = t & 3;
    const float* src = (vrow < 64) ? (Ww + (size_t)vrow * D_DIM)
                                   : (Wn + (size_t)(vrow - 64) * D_DIM);
    const float4 a = *reinterpret_cast<const float4*>(src + kc * 32 + c4 * 8);
    const float4 b = *reinterpret_cast<const float4*>(src + kc * 32 + c4 * 8 + 4);
    const float f[8] = {a.x, a.y, a.z, a.w, b.x, b.y, b.z, b.w};
    union { _Float16 h[8]; uint4 q; } P0, P1;
#pragma unroll
    for (int i = 0; i < 8; ++i) {
        _Float16 lo = (_Float16)f[i];
        P0.h[i] = lo;
        P1.h[i] = (_Float16)((f[i] - (float)lo) * 2048.0f);
    }
    const int sc = c4 ^ ((vrow >> 2) & 3);
    char* dst = Wp + (size_t)kc * WTILE_BYTES + vrow * 64 + sc * 16;
    *reinterpret_cast<uint4*>(dst)        = P0.q;
    *reinterpret_cast<uint4*>(dst + 8192) = P1.q;
}

__global__ __launch_bounds__(256, 4)
void router_kernel(const float* __restrict__ h,
                   const float* __restrict__ bw,
                   const float* __restrict__ bn,
                   const float* __restrict__ noise,
                   const char* __restrict__ Wp,
                   float* __restrict__ out_gates,
                   float* __restrict__ out_ix,
                   float* __restrict__ out_full)
{
    __shared__ __align__(16) char smem[32768];   // 4 waves x 8KB (2-deep W); epilogue overlay

    const int t = threadIdx.x;
    const int lane = t & 63, w = t >> 6;   // wave w -> vcols w*32..+31, full K
    const int c = lane & 15, kg = lane >> 4;
    const int row0 = blockIdx.x * 16;      // 2048 blocks x 16 rows

    // h: per-lane 32B per k-tile, row = row0+c (all 4 waves read same bytes -> L1)
    const float* hp = h + (size_t)(row0 + c) * D_DIM + kg * 8;
    // W slice source (per-lane): + tile*16384 + p*8192 + i2*1024
    const char* wp0 = Wp + w * 2048 + lane * 16;
    // wave-private LDS region: 2 buffers x (2 planes x 2KB)
    char* wlds = smem + w * 8192;

    // A-frag byte offsets within a buffer (sw independent of vt/w)
    const int sw = (kg ^ ((c >> 2) & 3)) * 16;
    const int aoff00 = c * 64 + sw;                  // vt0 plane0
    const int aoff01 = 2048 + c * 64 + sw;           // vt0 plane1
    const int aoff10 = 1024 + c * 64 + sw;           // vt1 plane0
    const int aoff11 = 3072 + c * 64 + sw;           // vt1 plane1

    f32x4 grp0 = (f32x4)0.0f, grp1 = (f32x4)0.0f;
    f32x4 sA0  = (f32x4)0.0f, sA1  = (f32x4)0.0f;
    f32x4 aM0  = (f32x4)0.0f, aM1  = (f32x4)0.0f;

    float4 hA0, hA1, hB0, hB1, hC0, hC1, hD0, hD1;

    // ---- prologue: W(0), h(0), W(1), h(1), h(2)  [issue order matters for vmcnt] ----
#pragma unroll
    for (int p = 0; p < 2; ++p)
#pragma unroll
        for (int i2 = 0; i2 < 2; ++i2)
            gl16(wlds + p * 2048 + i2 * 1024, wp0 + p * 8192 + i2 * 1024);
    hA0 = *reinterpret_cast<const float4*>(hp);
    hA1 = *reinterpret_cast<const float4*>(hp + 4);
#pragma unroll
    for (int p = 0; p < 2; ++p)
#pragma unroll
        for (int i2 = 0; i2 < 2; ++i2)
            gl16(wlds + 4096 + p * 2048 + i2 * 1024,
                 wp0 + WTILE_BYTES + p * 8192 + i2 * 1024);
    hB0 = *reinterpret_cast<const float4*>(hp + 32);
    hB1 = *reinterpret_cast<const float4*>(hp + 36);
    hC0 = *reinterpret_cast<const float4*>(hp + 64);
    hC1 = *reinterpret_cast<const float4*>(hp + 68);
    asm volatile("s_waitcnt vmcnt(8)" ::: "memory");   // W(0)+h(0) retired
    __builtin_amdgcn_sched_barrier(0);

    // ---- main loop: zero barriers; per-wave counted vmcnt only ----
#define TILE_BODY(TL, BUFSEL, HC0v, HC1v, HN0v, HN1v)                          \
    {                                                                          \
        const int tl = (TL);                                                   \
        char* bufc = wlds + (BUFSEL) * 4096;                                   \
        const f16x8 A00 = *reinterpret_cast<const f16x8*>(bufc + aoff00);      \
        const f16x8 A01 = *reinterpret_cast<const f16x8*>(bufc + aoff01);      \
        const f16x8 A10 = *reinterpret_cast<const f16x8*>(bufc + aoff10);      \
        const f16x8 A11 = *reinterpret_cast<const f16x8*>(bufc + aoff11);      \
        asm volatile("s_waitcnt lgkmcnt(0)" ::: "memory");                     \
        __builtin_amdgcn_sched_barrier(0);                                     \
        if (tl + 2 < NT) {   /* W(t+2) -> same buffer (reads above are done) */ \
            const char* ws = wp0 + (size_t)(tl + 2) * WTILE_BYTES;             \
            gl16(bufc,        ws);                                             \
            gl16(bufc + 1024, ws + 1024);                                      \
            gl16(bufc + 2048, ws + 8192);                                      \
            gl16(bufc + 3072, ws + 9216);                                      \
        }                                                                      \
        if (tl + 3 < NT) {                                                     \
            HN0v = *reinterpret_cast<const float4*>(hp + (tl + 3) * 32);       \
            HN1v = *reinterpret_cast<const float4*>(hp + (tl + 3) * 32 + 4);   \
        }                                                                      \
        f16x8 B0, B1;                                                          \
        {                                                                      \
            const float ff[8] = {HC0v.x, HC0v.y, HC0v.z, HC0v.w,               \
                                 HC1v.x, HC1v.y, HC1v.z, HC1v.w};              \
            _Pragma("unroll")                                                  \
            for (int i = 0; i < 8; ++i) {                                      \
                _Float16 lo = (_Float16)ff[i];                                 \
                B0[i] = lo;                                                    \
                B1[i] = (_Float16)((ff[i] - (float)lo) * 2048.0f);             \
            }                                                                  \
        }                                                                      \
        grp0 = MFMA16F(A00, B0, grp0);                                         \
        aM0  = MFMA16F(A00, B1, aM0);                                          \
        aM0  = MFMA16F(A01, B0, aM0);                                          \
        grp1 = MFMA16F(A10, B0, grp1);                                         \
        aM1  = MFMA16F(A10, B1, aM1);                                          \
        aM1  = MFMA16F(A11, B0, aM1);                                          \
        if (tl < 125)       asm volatile("s_waitcnt vmcnt(8)" ::: "memory");   \
        else if (tl == 125) asm volatile("s_waitcnt vmcnt(6)" ::: "memory");   \
        else                asm volatile("s_waitcnt vmcnt(0)" ::: "memory");   \
        __builtin_amdgcn_sched_barrier(0);                                     \
    }

    for (int tt = 0; tt < NT / 4; ++tt) {
        const int b = 4 * tt;
        TILE_BODY(b,     0, hA0, hA1, hD0, hD1)
        TILE_BODY(b + 1, 1, hB0, hB1, hA0, hA1)
        TILE_BODY(b + 2, 0, hC0, hC1, hB0, hB1)
        TILE_BODY(b + 3, 1, hD0, hD1, hC0, hC1)
        if ((tt & 3) == 3) {   // fold every 16 k-tiles (same as passing R8/R14)
#pragma unroll
            for (int e = 0; e < 4; ++e) {
                sA0[e] += grp0[e]; sA1[e] += grp1[e];
            }
            grp0 = (f32x4)0.0f; grp1 = (f32x4)0.0f;
        }
    }
#undef TILE_BODY

    // ---- epilogue: stage logits to LDS (overlay W buffers) ----
    __syncthreads();
    float* lw_s = reinterpret_cast<float*>(smem);   // [16][65]
    float* ln_s = lw_s + 16 * 65;                   // [16][65]
    {
        // D layout: row (M=vcol) = kg*4+e, col (N=h-row) = c
        float* dst = (w < 2) ? lw_s : ln_s;
        const int eb = (w & 1) * 32;
#pragma unroll
        for (int e = 0; e < 4; ++e) {
            dst[c * 65 + eb +      kg * 4 + e] = sA0[e] + aM0[e] * 4.8828125e-4f;
            dst[c * 65 + eb + 16 + kg * 4 + e] = sA1[e] + aM1[e] * 4.8828125e-4f;
        }
    }
    __syncthreads();

    // ---- noisy + top-8 + softmaxes: wave w -> rows w*4..+3, lane = expert ----
    const float bwv = bw[lane];
    const float bnv = bn[lane];
    for (int q = 0; q < 4; ++q) {
        const int lrow = w * 4 + q;
        const int grow = row0 + lrow;
        const float lwv = lw_s[lrow * 65 + lane] + bwv;
        const float lnv = ln_s[lrow * 65 + lane] + bnv;
        const float nz  = noise[(size_t)grow * 64 + lane];
        const float v   = lwv + nz * softplus_f(lnv);

        float cur2 = v;
        float m8 = 0.0f;
        int winIdx = 0;
        bool picked = false;
#pragma unroll
        for (int r = 0; r < 8; ++r) {
            float bvv = cur2;
            int   bi  = lane;
#pragma unroll
            for (int off = 32; off; off >>= 1) {
                const float ov = __shfl_xor(bvv, off);
                const int   oi = __shfl_xor(bi, off);
                if (ov > bvv || (ov == bvv && oi < bi)) { bvv = ov; bi = oi; }
            }
            if (r == 0) m8 = bvv;
            if (lane == r) winIdx = bi;
            if (lane == bi) { picked = true; cur2 = -INFINITY; }
        }

        const float pf = expf(v - m8);
        const float pg = picked ? pf : 0.0f;
        float sf = pf, sg = pg;
#pragma unroll
        for (int off = 32; off; off >>= 1) {
            sf += __shfl_xor(sf, off);
            sg += __shfl_xor(sg, off);
        }

        out_full [(size_t)grow * 64 + lane] = pf / sf;
        out_gates[(size_t)grow * 64 + lane] = pg / sg;
        if (lane < 8) out_ix[(size_t)grow * 8 + lane] = (float)winIdx;
    }
}

extern "C" void kernel_launch(void* const* d_in, const int* in_sizes, int n_in,
                              void* d_out, int out_size, void* d_ws, size_t ws_size,
                              hipStream_t stream) {
    const float* h  = (const float*)d_in[0];
    const float* Ww = (const float*)d_in[1];
    const float* bw = (const float*)d_in[2];
    const float* Wn = (const float*)d_in[3];
    const float* bn = (const float*)d_in[4];
    const float* nz = (const float*)d_in[5];

    const int rows = in_sizes[5] / 64;   // 32768

    float* out = (float*)d_out;
    float* og = out;
    float* oi = out + (size_t)rows * 64;
    float* of = out + (size_t)rows * 64 + (size_t)rows * 8;

    char* Wp = (char*)d_ws;   // 128 k-tiles * 16384 B = 2 MB

    hipLaunchKernelGGL(wconv_kernel, dim3(256), dim3(256), 0, stream, Ww, Wn, Wp);
    hipLaunchKernelGGL(router_kernel, dim3(rows / 16), dim3(256), 0, stream,
                       h, bw, bn, nz, Wp, og, oi, of);
}

// Round 16
// 305.711 us; speedup vs baseline: 1.4257x; 1.4257x over previous
//
#include <hip/hip_runtime.h>
#include <hip/hip_bf16.h>
#include <math.h>

// NoisyTopkRouter: rows=32768, D=4096, E=64, k=8.
// R16: m201-style 8-phase schedule. 256 blocks (1/CU), 512 thr (8 waves 2x4),
// BM=128, BN=128, BK=64, 64 K-steps. Per phase: {A ds_reads (+B at ph0/4) |
// one staging action | barrier | lgkm(0) | setprio(1) 6xMFMA setprio(0) |
// barrier}. h reg-staged->fp16x2 planes (stride-144), W gl16-DMA from d_ws
// image. Counted vmcnt: h at ph6 (vmcnt(4)), W drained at ph7 end.
// fp16x2 split (main + mid@2^11), fold-16-tiles. Output (fp32):
// gates[rows*64] | ix[rows*8] | full[rows*64]

typedef __attribute__((ext_vector_type(8))) _Float16 f16x8;
typedef __attribute__((ext_vector_type(4))) float f32x4;
typedef unsigned int u32;

#define D_DIM 4096
#define NSTEP 64
#define WTILE 16384
#define ABUF 36864            // A region: 2 planes x 128 rows x 144B
#define BUF_BYTES 69632       // A 36864 + W 32768
#define SMEM_BYTES 139264

__device__ __forceinline__ float softplus_f(float x) {
    return fmaxf(x, 0.0f) + log1pf(expf(-fabsf(x)));
}

__device__ __forceinline__ void gl16(void* lds, const void* g) {
    __builtin_amdgcn_global_load_lds(
        (const __attribute__((address_space(1))) u32*)g,
        (__attribute__((address_space(3))) u32*)lds, 16, 0, 0);
}

#define MFMA16F(A, B, C) __builtin_amdgcn_mfma_f32_16x16x32_f16((A), (B), (C), 0, 0, 0)

// ---- W pre-conversion (unchanged): 2 fp16 planes (p0=f16(w), p1=f16((w-p0)*2048)),
// per-32k-tile 16KB image, chunk-swizzled sc = c4 ^ ((vrow>>2)&3)
__global__ __launch_bounds__(256)
void wconv_kernel(const float* __restrict__ Ww, const float* __restrict__ Wn,
                  char* __restrict__ Wp)
{
    const int bid = blockIdx.x;            // 256 blocks
    const int kc = bid >> 1, half = bid & 1;
    const int t = threadIdx.x;
    const int vrow = half * 64 + (t >> 2);
    const int c4 = t & 3;
    const float* src = (vrow < 64) ? (Ww + (size_t)vrow * D_DIM)
                                   : (Wn + (size_t)(vrow - 64) * D_DIM);
    const float4 a = *reinterpret_cast<const float4*>(src + kc * 32 + c4 * 8);
    const float4 b = *reinterpret_cast<const float4*>(src + kc * 32 + c4 * 8 + 4);
    const float f[8] = {a.x, a.y, a.z, a.w, b.x, b.y, b.z, b.w};
    union { _Float16 h[8]; uint4 q; } P0, P1;
#pragma unroll
    for (int i = 0; i < 8; ++i) {
        _Float16 lo = (_Float16)f[i];
        P0.h[i] = lo;
        P1.h[i] = (_Float16)((f[i] - (float)lo) * 2048.0f);
    }
    const int sc = c4 ^ ((vrow >> 2) & 3);
    char* dst = Wp + (size_t)kc * WTILE + vrow * 64 + sc * 16;
    *reinterpret_cast<uint4*>(dst)        = P0.q;
    *reinterpret_cast<uint4*>(dst + 8192) = P1.q;
}

// exact fp16x2 split of 8 fp32 (two float4) -> 16B lo + 16B hi
#define CV(DL, DH, V0, V1) {                                                          \
    union { _Float16 q[8]; uint4 u; } Lu, Hu;                                         \
    _Float16 x_;                                                                      \
    x_ = (_Float16)(V0).x; Lu.q[0] = x_; Hu.q[0] = (_Float16)(((V0).x - (float)x_) * 2048.0f); \
    x_ = (_Float16)(V0).y; Lu.q[1] = x_; Hu.q[1] = (_Float16)(((V0).y - (float)x_) * 2048.0f); \
    x_ = (_Float16)(V0).z; Lu.q[2] = x_; Hu.q[2] = (_Float16)(((V0).z - (float)x_) * 2048.0f); \
    x_ = (_Float16)(V0).w; Lu.q[3] = x_; Hu.q[3] = (_Float16)(((V0).w - (float)x_) * 2048.0f); \
    x_ = (_Float16)(V1).x; Lu.q[4] = x_; Hu.q[4] = (_Float16)(((V1).x - (float)x_) * 2048.0f); \
    x_ = (_Float16)(V1).y; Lu.q[5] = x_; Hu.q[5] = (_Float16)(((V1).y - (float)x_) * 2048.0f); \
    x_ = (_Float16)(V1).z; Lu.q[6] = x_; Hu.q[6] = (_Float16)(((V1).z - (float)x_) * 2048.0f); \
    x_ = (_Float16)(V1).w; Lu.q[7] = x_; Hu.q[7] = (_Float16)(((V1).w - (float)x_) * 2048.0f); \
    *reinterpret_cast<uint4*>(DL) = Lu.u;                                             \
    *reinterpret_cast<uint4*>(DH) = Hu.u;                                             \
  }

#define NOP
#define NOPR
#define SH0 if (more) { hv0a = *reinterpret_cast<const float4*>(hp + hko); \
                        hv0b = *reinterpret_cast<const float4*>(hp + hko + 4); }
#define SH1 if (more) { hv1a = *reinterpret_cast<const float4*>(hp + hko + 32); \
                        hv1b = *reinterpret_cast<const float4*>(hp + hko + 36); }
#define SW0 if (more) gl16(nbuf + ABUF + 0 * 8192 + w * 1024, wS + 0 * 8192);
#define SW1 if (more) gl16(nbuf + ABUF + 1 * 8192 + w * 1024, wS + 1 * 8192);
#define SW2 if (more) gl16(nbuf + ABUF + 2 * 8192 + w * 1024, wS + 2 * 8192);
#define SW3 if (more) gl16(nbuf + ABUF + 3 * 8192 + w * 1024, wS + 3 * 8192);
#define SCONV if (more) {                                                     \
    asm volatile("s_waitcnt vmcnt(4)" ::: "memory");                          \
    __builtin_amdgcn_sched_barrier(0);                                        \
    CV(nbuf + hwb, nbuf + 18432 + hwb, hv0a, hv0b)                            \
    CV(nbuf + hwb + 64, nbuf + 18432 + hwb + 64, hv1a, hv1b)                  \
  }
#define PVM asm volatile("s_waitcnt vmcnt(0)" ::: "memory");

#define RBODY(KH) {                                                           \
    const int v0_ = wc * 32 + c;                                              \
    const int v1_ = v0_ + 16;                                                 \
    const char* wt_ = bufc + ABUF + (KH) * WTILE;                             \
    const int o0_ = v0_ * 64 + ((kg ^ ((v0_ >> 2) & 3)) * 16);                \
    const int o1_ = v1_ * 64 + ((kg ^ ((v1_ >> 2) & 3)) * 16);                \
    B00 = *reinterpret_cast<const f16x8*>(wt_ + o0_);                         \
    B01 = *reinterpret_cast<const f16x8*>(wt_ + 8192 + o0_);                  \
    B10 = *reinterpret_cast<const f16x8*>(wt_ + o1_);                        \
    B11 = *reinterpret_cast<const f16x8*>(wt_ + 8192 + o1_);                  \
  }
#define RB0 RBODY(0)
#define RB1 RBODY(1)

// one phase: A reads (+opt B) | staging action | barrier | lgkm0 | 6 MFMA | barrier
#define PH(MT, KH, READB, STAGE, POST)                                        \
  {                                                                           \
    const int arow_ = wr * 64 + (MT) * 16 + c;                                \
    const int ab_ = arow_ * 144 + ((KH) * 4 + kg) * 16;                       \
    const f16x8 A0_ = *reinterpret_cast<const f16x8*>(bufc + ab_);            \
    const f16x8 A1_ = *reinterpret_cast<const f16x8*>(bufc + 18432 + ab_);    \
    READB                                                                     \
    STAGE                                                                     \
    __builtin_amdgcn_s_barrier();                                             \
    asm volatile("s_waitcnt lgkmcnt(0)" ::: "memory");                        \
    __builtin_amdgcn_sched_barrier(0);                                        \
    __builtin_amdgcn_s_setprio(1);                                            \
    grp[(MT)][0] = MFMA16F(A0_, B00, grp[(MT)][0]);                           \
    aM [(MT)][0] = MFMA16F(A0_, B01, aM [(MT)][0]);                           \
    aM [(MT)][0] = MFMA16F(A1_, B00, aM [(MT)][0]);                           \
    grp[(MT)][1] = MFMA16F(A0_, B10, grp[(MT)][1]);                           \
    aM [(MT)][1] = MFMA16F(A0_, B11, aM [(MT)][1]);                           \
    aM [(MT)][1] = MFMA16F(A1_, B10, aM [(MT)][1]);                           \
    __builtin_amdgcn_s_setprio(0);                                            \
    POST                                                                      \
    __builtin_amdgcn_sched_barrier(0);                                        \
    __builtin_amdgcn_s_barrier();                                             \
    __builtin_amdgcn_sched_barrier(0);                                        \
  }

__global__ __launch_bounds__(512, 2)
void router_kernel(const float* __restrict__ h,
                   const float* __restrict__ bw,
                   const float* __restrict__ bn,
                   const float* __restrict__ noise,
                   const char* __restrict__ Wp,
                   float* __restrict__ out_gates,
                   float* __restrict__ out_ix,
                   float* __restrict__ out_full)
{
    __shared__ __align__(16) char smem[SMEM_BYTES];

    const int t = threadIdx.x;
    const int lane = t & 63, w = t >> 6;    // 8 waves
    const int c = lane & 15, kg = lane >> 4;
    const int wr = w >> 2, wc = w & 3;      // rows wr*64.., vcols wc*32..
    const int row0 = blockIdx.x * 128;      // 256 blocks

    // h staging: thread -> row t>>2 (0..127), granule-pair hg / hg+4
    const int hrow = t >> 2, hg = t & 3;
    const float* hp = h + (size_t)(row0 + hrow) * D_DIM + hg * 8;
    const int hwb = hrow * 144 + hg * 16;
    const char* wlane = Wp + w * 1024 + lane * 16;

    f32x4 grp[4][2], aM[4][2], sAc[4][2];
#pragma unroll
    for (int i = 0; i < 4; ++i)
#pragma unroll
        for (int j = 0; j < 2; ++j) {
            grp[i][j] = (f32x4)0.0f; aM[i][j] = (f32x4)0.0f; sAc[i][j] = (f32x4)0.0f;
        }

    f16x8 B00, B01, B10, B11;
    float4 hv0a, hv0b, hv1a, hv1b;

    // ---- prologue: stage step 0 into buf 0 ----
    hv0a = *reinterpret_cast<const float4*>(hp);
    hv0b = *reinterpret_cast<const float4*>(hp + 4);
    hv1a = *reinterpret_cast<const float4*>(hp + 32);
    hv1b = *reinterpret_cast<const float4*>(hp + 36);
#pragma unroll
    for (int i = 0; i < 4; ++i)
        gl16(smem + ABUF + i * 8192 + w * 1024, wlane + (size_t)i * 8192);
    asm volatile("s_waitcnt vmcnt(4)" ::: "memory");
    __builtin_amdgcn_sched_barrier(0);
    CV(smem + hwb, smem + 18432 + hwb, hv0a, hv0b)
    CV(smem + hwb + 64, smem + 18432 + hwb + 64, hv1a, hv1b)
    asm volatile("s_waitcnt vmcnt(0) lgkmcnt(0)" ::: "memory");
    __builtin_amdgcn_sched_barrier(0);
    __builtin_amdgcn_s_barrier();
    __builtin_amdgcn_sched_barrier(0);

    // ---- main loop: 64 K-steps x 8 phases ----
    for (int s = 0; s < NSTEP; ++s) {
        const bool more = (s + 1 < NSTEP);
        const char* bufc = smem + (s & 1) * BUF_BYTES;
        char* nbuf = smem + ((s + 1) & 1) * BUF_BYTES;
        const size_t hko = (size_t)(s + 1) * 64;
        const char* wS = Wp + (size_t)(s + 1) * 32768 + w * 1024 + lane * 16;

        PH(0, 0, RB0,  SH0,   NOP)
        PH(1, 0, NOPR, SH1,   NOP)
        PH(2, 0, NOPR, SW0,   NOP)
        PH(3, 0, NOPR, SW1,   NOP)
        PH(0, 1, RB1,  SW2,   NOP)
        PH(1, 1, NOPR, SW3,   NOP)
        PH(2, 1, NOPR, SCONV, NOP)
        PH(3, 1, NOPR, NOP,   PVM)

        if ((s & 7) == 7) {
#pragma unroll
            for (int mt = 0; mt < 4; ++mt)
#pragma unroll
                for (int nt = 0; nt < 2; ++nt) {
#pragma unroll
                    for (int e = 0; e < 4; ++e) sAc[mt][nt][e] += grp[mt][nt][e];
                    grp[mt][nt] = (f32x4)0.0f;
                }
        }
    }

    // ---- logits -> LDS overlay ----
    __syncthreads();
    float* lw_s = reinterpret_cast<float*>(smem);     // [128][65]
    float* ln_s = lw_s + 128 * 65;                    // [128][65]
    {
        float* dst = (wc < 2) ? lw_s : ln_s;
        const int eb = (wc & 1) * 32;
#pragma unroll
        for (int mt = 0; mt < 4; ++mt)
#pragma unroll
            for (int nt = 0; nt < 2; ++nt)
#pragma unroll
                for (int e = 0; e < 4; ++e) {
                    const int rowl = wr * 64 + mt * 16 + kg * 4 + e;
                    dst[rowl * 65 + eb + nt * 16 + c] =
                        sAc[mt][nt][e] + aM[mt][nt][e] * 4.8828125e-4f; // 2^-11
                }
    }
    __syncthreads();

    // ---- noisy + top-8 + softmaxes: wave w -> rows w*16..+15, lane = expert ----
    const float bwv = bw[lane];
    const float bnv = bn[lane];
    for (int q = 0; q < 16; ++q) {
        const int lrow = w * 16 + q;
        const int grow = row0 + lrow;
        const float lwv = lw_s[lrow * 65 + lane] + bwv;
        const float lnv = ln_s[lrow * 65 + lane] + bnv;
        const float nz  = noise[(size_t)grow * 64 + lane];
        const float v   = lwv + nz * softplus_f(lnv);

        float cur2 = v;
        float m8 = 0.0f;
        int winIdx = 0;
        bool picked = false;
#pragma unroll
        for (int r = 0; r < 8; ++r) {
            float bvv = cur2;
            int   bi  = lane;
#pragma unroll
            for (int off = 32; off; off >>= 1) {
                const float ov = __shfl_xor(bvv, off);
                const int   oi = __shfl_xor(bi, off);
                if (ov > bvv || (ov == bvv && oi < bi)) { bvv = ov; bi = oi; }
            }
            if (r == 0) m8 = bvv;
            if (lane == r) winIdx = bi;
            if (lane == bi) { picked = true; cur2 = -INFINITY; }
        }

        const float pf = expf(v - m8);
        const float pg = picked ? pf : 0.0f;
        float sf = pf, sg = pg;
#pragma unroll
        for (int off = 32; off; off >>= 1) {
            sf += __shfl_xor(sf, off);
            sg += __shfl_xor(sg, off);
        }

        out_full [(size_t)grow * 64 + lane] = pf / sf;
        out_gates[(size_t)grow * 64 + lane] = pg / sg;
        if (lane < 8) out_ix[(size_t)grow * 8 + lane] = (float)winIdx;
    }
}

extern "C" void kernel_launch(void* const* d_in, const int* in_sizes, int n_in,
                              void* d_out, int out_size, void* d_ws, size_t ws_size,
                              hipStream_t stream) {
    const float* h  = (const float*)d_in[0];
    const float* Ww = (const float*)d_in[1];
    const float* bw = (const float*)d_in[2];
    const float* Wn = (const float*)d_in[3];
    const float* bn = (const float*)d_in[4];
    const float* nz = (const float*)d_in[5];

    const int rows = in_sizes[5] / 64;   // 32768

    float* out = (float*)d_out;
    float* og = out;
    float* oi = out + (size_t)rows * 64;
    float* of = out + (size_t)rows * 64 + (size_t)rows * 8;

    char* Wp = (char*)d_ws;   // 128 k-tiles * 16384 B = 2 MB

    hipLaunchKernelGGL(wconv_kernel, dim3(256), dim3(256), 0, stream, Ww, Wn, Wp);
    hipLaunchKernelGGL(router_kernel, dim3(rows / 128), dim3(512), 0, stream,
                       h, bw, bn, nz, Wp, og, oi, of);
}